// Round 3
// baseline (271.938 us; speedup 1.0000x reference)
//
#include <hip/hip_runtime.h>
#include <hip/hip_bf16.h>

// ---------------------------------------------------------------------------
// CVXPolicy_DoubleIntegrator, R3: weights-resident LDS, 16 waves/block.
//
// Packed weights (bf16, scatter folded into W3, t-row of W1 removed):
//   PW1: frag (kt*7+nt), kt<6, nt<7        -> shorts [0, 21504)
//   PW2: frag 42+kt*7+nt, kt<4, nt<7       -> shorts [21504, 35840)
//   PW3: frag 70+kt*6+nt, kt<4, nt<6       -> shorts [35840, 48128)
//   floats at short-index 48128: w0[112], b1[112], b2[112], bq[96]
// frag = 512 shorts: e = lane*8+j -> B[k = kt*32+(lane>>4)*8+j][n = nt*16+(lane&15)]
//
// MFMA 16x16x32 bf16 layouts (verified R1/R2, passing):
//   A:   lane -> A[m = lane&15][k = (lane>>4)*8 + j]
//   C/D: lane -> col = lane&15, row = (lane>>4)*4 + reg
//
// Main: 1024 thr (16 waves) x 256 blocks, 1 block/CU (LDS-capped), 16 rows
// per wave, 2 tiles of 256 rows per block, ONE barrier, waves independent.
// ---------------------------------------------------------------------------

typedef __attribute__((ext_vector_type(8))) short short8;
typedef __attribute__((ext_vector_type(4))) short short4v;
typedef __attribute__((ext_vector_type(4))) float f32x4;

#define HST 116  // hbuf row stride in shorts (232 B: 8B-aligned, 2-way banks max)

__device__ __forceinline__ unsigned short f2bf(float f) {
  unsigned u = __float_as_uint(f);
  u += 0x7fffu + ((u >> 16) & 1u);  // RNE (finite values only)
  return (unsigned short)(u >> 16);
}
__device__ __forceinline__ float tanh_fast(float x) {
  float ax = fabsf(x);
  float e = __builtin_amdgcn_exp2f(ax * -2.88539008177792681f);  // exp(-2ax)
  float r = (1.f - e) * __builtin_amdgcn_rcpf(1.f + e);
  return copysignf(r, x);
}

// ---------------------------------------------------------------------------
// Prep: pack weights bf16, fold scatter into W3, drop t-row (kept as w0 f32).
// ---------------------------------------------------------------------------
__global__ void cvx_prep(const float* __restrict__ W1, const float* __restrict__ b1,
                         const float* __restrict__ W2, const float* __restrict__ b2,
                         const float* __restrict__ W3, const float* __restrict__ b3,
                         short* __restrict__ pw) {
  int idx = blockIdx.x * 256 + threadIdx.x;

  if (idx < 21504) {                        // PW1: 6 kt * 7 nt * 512
    int kt = idx / 3584, rem = idx % 3584;
    int nt = rem / 512, e = rem % 512;
    int lane = e >> 3, j = e & 7;
    int k = kt * 32 + (lane >> 4) * 8 + j;  // z index; W1 row k+1
    int n = nt * 16 + (lane & 15);
    float wv = (n < 100) ? W1[(k + 1) * 100 + n] : 0.f;
    pw[(kt * 7 + nt) * 512 + e] = (short)f2bf(wv);
    return;
  }
  idx -= 21504;
  if (idx < 14336) {                        // PW2: 4 kt * 7 nt * 512
    int kt = idx / 3584, rem = idx % 3584;
    int nt = rem / 512, e = rem % 512;
    int lane = e >> 3, j = e & 7;
    int k = kt * 32 + (lane >> 4) * 8 + j;
    int n = nt * 16 + (lane & 15);
    float wv = (k < 100 && n < 100) ? W2[k * 100 + n] : 0.f;
    pw[21504 + (kt * 7 + nt) * 512 + e] = (short)f2bf(wv);
    return;
  }
  idx -= 14336;
  if (idx < 12288) {                        // PW3 folded: 4 kt * 6 nt * 512
    int kt = idx / 3072, rem = idx % 3072;
    int nt = rem / 512, e = rem % 512;
    int lane = e >> 3, j = e & 7;
    int k = kt * 32 + (lane >> 4) * 8 + j;
    int u = nt * 16 + (lane & 15);          // u < 96
    float wv = 0.f;
    if (k < 100) {
      const float* wr = W3 + k * 192;
      if (u <= 31) wv += wr[3 * u + 3];                     // u = i
      if ((u & 1) == 0 && u <= 62) wv += wr[2 * u + 4];     // u = 2i
      if (u % 3 == 0 && u <= 93) wv += wr[(5 * u) / 3 + 5]; // u = 3i
    }
    pw[35840 + (kt * 6 + nt) * 512 + e] = (short)f2bf(wv);
    return;
  }
  idx -= 12288;
  float* cb = (float*)(pw + 48128);
  if (idx < 112) { cb[idx] = (idx < 100) ? W1[idx] : 0.f; return; }        // w0 = W1 row 0
  idx -= 112;
  if (idx < 112) { cb[112 + idx] = (idx < 100) ? b1[idx] : 0.f; return; }
  idx -= 112;
  if (idx < 112) { cb[224 + idx] = (idx < 100) ? b2[idx] : 0.f; return; }
  idx -= 112;
  if (idx < 96) {
    int u = idx;
    float v = 0.f;
    if (u <= 31) v += b3[3 * u + 3];
    if ((u & 1) == 0 && u <= 62) v += b3[2 * u + 4];
    if (u % 3 == 0 && u <= 93) v += b3[(5 * u) / 3 + 5];
    cb[336 + u] = v;
  }
}

// ---------------------------------------------------------------------------
// Main fused kernel: 16 waves, 16 rows/wave, 2 tiles of 256 rows per block.
// ---------------------------------------------------------------------------
__global__ __launch_bounds__(1024, 4) void cvx_main(
    const float* __restrict__ zin, const float* __restrict__ tin,
    const short* __restrict__ pw, float* __restrict__ out) {
  __shared__ __align__(16) short wbuf[48128];         // 96,256 B: all weights
  __shared__ __align__(16) short hbuf[16 * 16 * HST]; // 59,392 B: per-wave h
  __shared__ __align__(16) float cbs[436];            //  1,744 B: w0,b1,b2,bq

  const int tid = threadIdx.x;
  const int wid = tid >> 6;
  const int lane = tid & 63;
  const int l15 = lane & 15;
  const int qd = lane >> 4;

  // stage ALL weights into LDS (once per block)
  for (int f = wid; f < 94; f += 16) {
    const short* g = pw + f * 512 + lane * 8;
    __builtin_amdgcn_global_load_lds(
        (const __attribute__((address_space(1))) void*)g,
        (__attribute__((address_space(3))) void*)&wbuf[f * 512], 16, 0, 0);
  }
  if (tid < 436) cbs[tid] = ((const float*)(pw + 48128))[tid];

  const int r0 = blockIdx.x * 512 + wid * 16;  // wave's first row (tile 0)
  const int hb = wid * 16 * HST;

  // prefetch tile 0 z,t into registers (overlaps weight staging)
  f32x4 zc[6][2];
  float tv;
  {
    const float* zr = zin + (size_t)(r0 + l15) * 192 + qd * 8;
#pragma unroll
    for (int kt = 0; kt < 6; kt++) {
      zc[kt][0] = *(const f32x4*)(zr + kt * 32);
      zc[kt][1] = *(const f32x4*)(zr + kt * 32 + 4);
    }
    tv = tin[r0 + l15];
  }

  __syncthreads();  // the only barrier: weights resident from here on

  auto ldh = [&](int off) -> short8 {   // 8B-aligned LDS read of 8 shorts
    short4v a = *(const short4v*)&hbuf[off];
    short4v b = *(const short4v*)&hbuf[off + 4];
    return __builtin_shufflevector(a, b, 0, 1, 2, 3, 4, 5, 6, 7);
  };

#pragma unroll 1
  for (int it = 0; it < 2; ++it) {
    const int rb = r0 + it * 256;

    // ---- build A fragments from prefetched z ----
    short8 XA[6];
#pragma unroll
    for (int kt = 0; kt < 6; kt++) {
      union { short8 s; __hip_bfloat162 h[4]; } u;
      f32x4 a = zc[kt][0], b = zc[kt][1];
      u.h[0] = __float22bfloat162_rn(make_float2(a[0], a[1]));
      u.h[1] = __float22bfloat162_rn(make_float2(a[2], a[3]));
      u.h[2] = __float22bfloat162_rn(make_float2(b[0], b[1]));
      u.h[3] = __float22bfloat162_rn(make_float2(b[2], b[3]));
      XA[kt] = u.s;
    }
    const float tcur = tv;

    // ---- issue next-tile loads now; results consumed at next XA build ----
    if (it == 0) {
      const float* zr = zin + (size_t)(rb + 256 + l15) * 192 + qd * 8;
#pragma unroll
      for (int kt = 0; kt < 6; kt++) {
        zc[kt][0] = *(const f32x4*)(zr + kt * 32);
        zc[kt][1] = *(const f32x4*)(zr + kt * 32 + 4);
      }
      tv = tin[rb + 256 + l15];
    }

    // ---- Layer 1: [16,192] x [192,112] ----
    f32x4 acc[7];
#pragma unroll
    for (int nt = 0; nt < 7; nt++) { f32x4 z4 = {0.f, 0.f, 0.f, 0.f}; acc[nt] = z4; }
#pragma unroll
    for (int kt = 0; kt < 6; kt++)
#pragma unroll
      for (int nt = 0; nt < 7; nt++) {
        short8 bf = *(const short8*)&wbuf[(kt * 7 + nt) * 512 + lane * 8];
        acc[nt] = __builtin_amdgcn_mfma_f32_16x16x32_bf16(XA[kt], bf, acc[nt], 0, 0, 0);
      }
    // t rank-1 fixup + bias + tanh -> hbuf
    float tr[4];
#pragma unroll
    for (int r = 0; r < 4; r++) tr[r] = __shfl(tcur, qd * 4 + r);
#pragma unroll
    for (int nt = 0; nt < 7; nt++) {
      float w0n = cbs[nt * 16 + l15];
      float b1n = cbs[112 + nt * 16 + l15];
#pragma unroll
      for (int r = 0; r < 4; r++) {
        float v = fmaf(tr[r], w0n, acc[nt][r] + b1n);
        hbuf[hb + (qd * 4 + r) * HST + nt * 16 + l15] = (short)f2bf(tanh_fast(v));
      }
    }

    // ---- Layer 2: [16,128] x [128,112] (kt=3: K rows 112..127 are B-zero) ----
    short8 HA[4];
    {
      int ro = hb + l15 * HST;
#pragma unroll
      for (int kt = 0; kt < 3; kt++) HA[kt] = ldh(ro + kt * 32 + qd * 8);
      HA[3] = ldh(ro + 96 + (qd & 1) * 8);  // qd>=2 reads valid-but-unused x B-zero
    }
#pragma unroll
    for (int nt = 0; nt < 7; nt++) { f32x4 z4 = {0.f, 0.f, 0.f, 0.f}; acc[nt] = z4; }
#pragma unroll
    for (int kt = 0; kt < 4; kt++)
#pragma unroll
      for (int nt = 0; nt < 7; nt++) {
        short8 bf = *(const short8*)&wbuf[(42 + kt * 7 + nt) * 512 + lane * 8];
        acc[nt] = __builtin_amdgcn_mfma_f32_16x16x32_bf16(HA[kt], bf, acc[nt], 0, 0, 0);
      }
#pragma unroll
    for (int nt = 0; nt < 7; nt++) {
      float b2n = cbs[224 + nt * 16 + l15];
#pragma unroll
      for (int r = 0; r < 4; r++)
        hbuf[hb + (qd * 4 + r) * HST + nt * 16 + l15] = (short)f2bf(tanh_fast(acc[nt][r] + b2n));
    }

    // ---- Layer 3 (scatter-folded): [16,128] x [128,96] -> q ----
    {
      int ro = hb + l15 * HST;
#pragma unroll
      for (int kt = 0; kt < 3; kt++) HA[kt] = ldh(ro + kt * 32 + qd * 8);
      HA[3] = ldh(ro + 96 + (qd & 1) * 8);
    }
    f32x4 qa[6];
#pragma unroll
    for (int nt = 0; nt < 6; nt++) { f32x4 z4 = {0.f, 0.f, 0.f, 0.f}; qa[nt] = z4; }
#pragma unroll
    for (int kt = 0; kt < 4; kt++)
#pragma unroll
      for (int nt = 0; nt < 6; nt++) {
        short8 bf = *(const short8*)&wbuf[(70 + kt * 6 + nt) * 512 + lane * 8];
        qa[nt] = __builtin_amdgcn_mfma_f32_16x16x32_bf16(HA[kt], bf, qa[nt], 0, 0, 0);
      }

    // ---- QP epilogue: r2 = ||q||^2, Newton s(1+s)^2 = r2, u = -q/(1+s) ----
#pragma unroll
    for (int nt = 0; nt < 6; nt++) {
      float bq = cbs[336 + nt * 16 + l15];
      qa[nt][0] += bq; qa[nt][1] += bq; qa[nt][2] += bq; qa[nt][3] += bq;
    }
    f32x4 rs = {0.f, 0.f, 0.f, 0.f};
#pragma unroll
    for (int nt = 0; nt < 6; nt++) rs += qa[nt] * qa[nt];
    float rv[4];
#pragma unroll
    for (int r = 0; r < 4; r++) {
      float v = rs[r];
      v += __shfl_xor(v, 1);
      v += __shfl_xor(v, 2);
      v += __shfl_xor(v, 4);
      v += __shfl_xor(v, 8);
      rv[r] = v;
    }
    float r2 = rv[l15 & 3];
    float s = __builtin_amdgcn_exp2f(__builtin_amdgcn_logf(r2) * 0.333333333333f);
#pragma unroll
    for (int itn = 0; itn < 8; itn++) {
      float one = 1.f + s;
      float fv = fmaf(s * one, one, -r2);
      float fp = one * fmaf(2.f, s, one);
      s = fmaxf(s - fv * __builtin_amdgcn_rcpf(fp), 0.f);
    }
    float myinv = -__builtin_amdgcn_rcpf(1.f + s);
#pragma unroll
    for (int r = 0; r < 4; r++) {
      float inv = __shfl(myinv, (lane & 48) | r);
      float* orow = out + (size_t)(rb + qd * 4 + r) * 96;
#pragma unroll
      for (int nt = 0; nt < 6; nt++)
        orow[nt * 16 + l15] = qa[nt][r] * inv;
    }
  }
}

extern "C" void kernel_launch(void* const* d_in, const int* in_sizes, int n_in,
                              void* d_out, int out_size, void* d_ws, size_t ws_size,
                              hipStream_t stream) {
  const float* z  = (const float*)d_in[0];
  const float* t  = (const float*)d_in[1];
  const float* W1 = (const float*)d_in[2];
  const float* b1 = (const float*)d_in[3];
  const float* W2 = (const float*)d_in[4];
  const float* b2 = (const float*)d_in[5];
  const float* W3 = (const float*)d_in[6];
  const float* b3 = (const float*)d_in[7];
  float* out = (float*)d_out;
  int B = in_sizes[0] / 192;                 // 131072

  short* pw = (short*)d_ws;                  // 97,984 bytes used
  cvx_prep<<<190, 256, 0, stream>>>(W1, b1, W2, b2, W3, b3, pw);
  cvx_main<<<B / 512, 1024, 0, stream>>>(z, t, pw, out);
}

// Round 4
// 193.383 us; speedup vs baseline: 1.4062x; 1.4062x over previous
//
#include <hip/hip_runtime.h>
#include <hip/hip_bf16.h>

// ---------------------------------------------------------------------------
// CVXPolicy_DoubleIntegrator, R4: weights-resident LDS, 16 waves, no spill.
//
// Packed weights (bf16, scatter folded into W3, t-row of W1 removed):
//   PW1: frag (kt*7+nt), kt<6, nt<7        -> shorts [0, 21504)
//   PW2: frag 42+kt*7+nt, kt<4, nt<7       -> shorts [21504, 35840)
//   PW3: frag 70+kt*6+nt, kt<4, nt<6       -> shorts [35840, 48128)
//   floats at short-index 48128: w0[112], b1[112], b2[112], bq[96]
// frag = 512 shorts: e = lane*8+j -> B[k = kt*32+(lane>>4)*8+j][n = nt*16+(lane&15)]
//
// MFMA 16x16x32 bf16 layouts (verified R1-R3, passing):
//   A:   lane -> A[m = lane&15][k = (lane>>4)*8 + j]
//   C/D: lane -> col = lane&15, row = (lane>>4)*4 + reg
//
// Main: 1024 thr (16 waves) x 512 blocks, 16 rows/wave, ONE 256-row pass per
// block, ONE barrier. z converted to bf16 BEFORE the barrier (vmcnt(0) is
// drained there anyway) so no f32 z state survives it -> no spills (R3 bug:
// launch_bounds(1024,4) forced 64 VGPR + 48-reg live prefetch => 174 MB of
// scratch traffic each way).
// ---------------------------------------------------------------------------

typedef __attribute__((ext_vector_type(8))) short short8;
typedef __attribute__((ext_vector_type(4))) short short4v;
typedef __attribute__((ext_vector_type(4))) float f32x4;

#define HST 116  // hbuf row stride in shorts (232 B: 8B-aligned)

__device__ __forceinline__ unsigned short f2bf(float f) {
  unsigned u = __float_as_uint(f);
  u += 0x7fffu + ((u >> 16) & 1u);  // RNE (finite values only)
  return (unsigned short)(u >> 16);
}
__device__ __forceinline__ float tanh_fast(float x) {
  float ax = fabsf(x);
  float e = __builtin_amdgcn_exp2f(ax * -2.88539008177792681f);  // exp(-2ax)
  float r = (1.f - e) * __builtin_amdgcn_rcpf(1.f + e);
  return copysignf(r, x);
}

// ---------------------------------------------------------------------------
// Prep: pack weights bf16, fold scatter into W3, drop t-row (kept as w0 f32).
// ---------------------------------------------------------------------------
__global__ void cvx_prep(const float* __restrict__ W1, const float* __restrict__ b1,
                         const float* __restrict__ W2, const float* __restrict__ b2,
                         const float* __restrict__ W3, const float* __restrict__ b3,
                         short* __restrict__ pw) {
  int idx = blockIdx.x * 256 + threadIdx.x;

  if (idx < 21504) {                        // PW1: 6 kt * 7 nt * 512
    int kt = idx / 3584, rem = idx % 3584;
    int nt = rem / 512, e = rem % 512;
    int lane = e >> 3, j = e & 7;
    int k = kt * 32 + (lane >> 4) * 8 + j;  // z index; W1 row k+1
    int n = nt * 16 + (lane & 15);
    float wv = (n < 100) ? W1[(k + 1) * 100 + n] : 0.f;
    pw[(kt * 7 + nt) * 512 + e] = (short)f2bf(wv);
    return;
  }
  idx -= 21504;
  if (idx < 14336) {                        // PW2: 4 kt * 7 nt * 512
    int kt = idx / 3584, rem = idx % 3584;
    int nt = rem / 512, e = rem % 512;
    int lane = e >> 3, j = e & 7;
    int k = kt * 32 + (lane >> 4) * 8 + j;
    int n = nt * 16 + (lane & 15);
    float wv = (k < 100 && n < 100) ? W2[k * 100 + n] : 0.f;
    pw[21504 + (kt * 7 + nt) * 512 + e] = (short)f2bf(wv);
    return;
  }
  idx -= 14336;
  if (idx < 12288) {                        // PW3 folded: 4 kt * 6 nt * 512
    int kt = idx / 3072, rem = idx % 3072;
    int nt = rem / 512, e = rem % 512;
    int lane = e >> 3, j = e & 7;
    int k = kt * 32 + (lane >> 4) * 8 + j;
    int u = nt * 16 + (lane & 15);          // u < 96
    float wv = 0.f;
    if (k < 100) {
      const float* wr = W3 + k * 192;
      if (u <= 31) wv += wr[3 * u + 3];                     // u = i
      if ((u & 1) == 0 && u <= 62) wv += wr[2 * u + 4];     // u = 2i
      if (u % 3 == 0 && u <= 93) wv += wr[(5 * u) / 3 + 5]; // u = 3i
    }
    pw[35840 + (kt * 6 + nt) * 512 + e] = (short)f2bf(wv);
    return;
  }
  idx -= 12288;
  float* cb = (float*)(pw + 48128);
  if (idx < 112) { cb[idx] = (idx < 100) ? W1[idx] : 0.f; return; }        // w0 = W1 row 0
  idx -= 112;
  if (idx < 112) { cb[112 + idx] = (idx < 100) ? b1[idx] : 0.f; return; }
  idx -= 112;
  if (idx < 112) { cb[224 + idx] = (idx < 100) ? b2[idx] : 0.f; return; }
  idx -= 112;
  if (idx < 96) {
    int u = idx;
    float v = 0.f;
    if (u <= 31) v += b3[3 * u + 3];
    if ((u & 1) == 0 && u <= 62) v += b3[2 * u + 4];
    if (u % 3 == 0 && u <= 93) v += b3[(5 * u) / 3 + 5];
    cb[336 + u] = v;
  }
}

// ---------------------------------------------------------------------------
// Main fused kernel: 16 waves x 16 rows, one 256-row pass per block.
// ---------------------------------------------------------------------------
__global__ __launch_bounds__(1024) void cvx_main(
    const float* __restrict__ zin, const float* __restrict__ tin,
    const short* __restrict__ pw, float* __restrict__ out) {
  __shared__ __align__(16) short wbuf[48128];         // 96,256 B: all weights
  __shared__ __align__(16) short hbuf[16 * 16 * HST]; // 59,392 B: per-wave h

  const int tid = threadIdx.x;
  const int wid = tid >> 6;
  const int lane = tid & 63;
  const int l15 = lane & 15;
  const int qd = lane >> 4;

  // stage ALL weights into LDS (once per block)
  for (int f = wid; f < 94; f += 16) {
    const short* g = pw + f * 512 + lane * 8;
    __builtin_amdgcn_global_load_lds(
        (const __attribute__((address_space(1))) void*)g,
        (__attribute__((address_space(3))) void*)&wbuf[f * 512], 16, 0, 0);
  }

  const int rb = blockIdx.x * 256 + wid * 16;  // wave's first row
  const int hb = wid * 16 * HST;
  const float* cb = (const float*)(pw + 48128);  // w0/b1/b2/bq (L1/L2-hot)

  // load z,t and convert to bf16 A-fragments BEFORE the barrier
  // (the barrier's vmcnt(0) drain covers these loads; converting here keeps
  //  only 12 bf16 regs live instead of 48 f32 -> no spills at 128-VGPR cap)
  short8 XA[6];
  float tcur;
  {
    const float* zr = zin + (size_t)(rb + l15) * 192 + qd * 8;
    f32x4 za[6], zb[6];
#pragma unroll
    for (int kt = 0; kt < 6; kt++) {
      za[kt] = *(const f32x4*)(zr + kt * 32);
      zb[kt] = *(const f32x4*)(zr + kt * 32 + 4);
    }
    tcur = tin[rb + l15];
#pragma unroll
    for (int kt = 0; kt < 6; kt++) {
      union { short8 s; __hip_bfloat162 h[4]; } u;
      u.h[0] = __float22bfloat162_rn(make_float2(za[kt][0], za[kt][1]));
      u.h[1] = __float22bfloat162_rn(make_float2(za[kt][2], za[kt][3]));
      u.h[2] = __float22bfloat162_rn(make_float2(zb[kt][0], zb[kt][1]));
      u.h[3] = __float22bfloat162_rn(make_float2(zb[kt][2], zb[kt][3]));
      XA[kt] = u.s;
    }
  }

  __syncthreads();  // the only barrier: weights resident from here on

  auto ldh = [&](int off) -> short8 {   // 8B-aligned LDS read of 8 shorts
    short4v a = *(const short4v*)&hbuf[off];
    short4v b = *(const short4v*)&hbuf[off + 4];
    return __builtin_shufflevector(a, b, 0, 1, 2, 3, 4, 5, 6, 7);
  };

  // ---- Layer 1: [16,192] x [192,112] ----
  f32x4 acc[7];
#pragma unroll
  for (int nt = 0; nt < 7; nt++) { f32x4 z4 = {0.f, 0.f, 0.f, 0.f}; acc[nt] = z4; }
#pragma unroll
  for (int kt = 0; kt < 6; kt++)
#pragma unroll
    for (int nt = 0; nt < 7; nt++) {
      short8 bf = *(const short8*)&wbuf[(kt * 7 + nt) * 512 + lane * 8];
      acc[nt] = __builtin_amdgcn_mfma_f32_16x16x32_bf16(XA[kt], bf, acc[nt], 0, 0, 0);
    }
  // t rank-1 fixup + bias + tanh -> hbuf
  float tr[4];
#pragma unroll
  for (int r = 0; r < 4; r++) tr[r] = __shfl(tcur, qd * 4 + r);
#pragma unroll
  for (int nt = 0; nt < 7; nt++) {
    float w0n = cb[nt * 16 + l15];
    float b1n = cb[112 + nt * 16 + l15];
#pragma unroll
    for (int r = 0; r < 4; r++) {
      float v = fmaf(tr[r], w0n, acc[nt][r] + b1n);
      hbuf[hb + (qd * 4 + r) * HST + nt * 16 + l15] = (short)f2bf(tanh_fast(v));
    }
  }

  // ---- Layer 2: [16,128] x [128,112] (K rows 100..127 are B-zero) ----
  short8 HA[4];
  {
    int ro = hb + l15 * HST;
#pragma unroll
    for (int kt = 0; kt < 3; kt++) HA[kt] = ldh(ro + kt * 32 + qd * 8);
    HA[3] = ldh(ro + 96 + (qd & 1) * 8);  // k>=100 lanes read zeros/B-zero
  }
#pragma unroll
  for (int nt = 0; nt < 7; nt++) { f32x4 z4 = {0.f, 0.f, 0.f, 0.f}; acc[nt] = z4; }
#pragma unroll
  for (int kt = 0; kt < 4; kt++)
#pragma unroll
    for (int nt = 0; nt < 7; nt++) {
      short8 bf = *(const short8*)&wbuf[(42 + kt * 7 + nt) * 512 + lane * 8];
      acc[nt] = __builtin_amdgcn_mfma_f32_16x16x32_bf16(HA[kt], bf, acc[nt], 0, 0, 0);
    }
#pragma unroll
  for (int nt = 0; nt < 7; nt++) {
    float b2n = cb[224 + nt * 16 + l15];
#pragma unroll
    for (int r = 0; r < 4; r++)
      hbuf[hb + (qd * 4 + r) * HST + nt * 16 + l15] = (short)f2bf(tanh_fast(acc[nt][r] + b2n));
  }

  // ---- Layer 3 (scatter-folded): [16,128] x [128,96] -> q ----
  {
    int ro = hb + l15 * HST;
#pragma unroll
    for (int kt = 0; kt < 3; kt++) HA[kt] = ldh(ro + kt * 32 + qd * 8);
    HA[3] = ldh(ro + 96 + (qd & 1) * 8);
  }
  f32x4 qa[6];
#pragma unroll
  for (int nt = 0; nt < 6; nt++) { f32x4 z4 = {0.f, 0.f, 0.f, 0.f}; qa[nt] = z4; }
#pragma unroll
  for (int kt = 0; kt < 4; kt++)
#pragma unroll
    for (int nt = 0; nt < 6; nt++) {
      short8 bf = *(const short8*)&wbuf[(70 + kt * 6 + nt) * 512 + lane * 8];
      qa[nt] = __builtin_amdgcn_mfma_f32_16x16x32_bf16(HA[kt], bf, qa[nt], 0, 0, 0);
    }

  // ---- QP epilogue: r2 = ||q||^2, Newton s(1+s)^2 = r2, u = -q/(1+s) ----
#pragma unroll
  for (int nt = 0; nt < 6; nt++) {
    float bq = cb[336 + nt * 16 + l15];
    qa[nt][0] += bq; qa[nt][1] += bq; qa[nt][2] += bq; qa[nt][3] += bq;
  }
  f32x4 rs = {0.f, 0.f, 0.f, 0.f};
#pragma unroll
  for (int nt = 0; nt < 6; nt++) rs += qa[nt] * qa[nt];
  float rv[4];
#pragma unroll
  for (int r = 0; r < 4; r++) {
    float v = rs[r];
    v += __shfl_xor(v, 1);
    v += __shfl_xor(v, 2);
    v += __shfl_xor(v, 4);
    v += __shfl_xor(v, 8);
    rv[r] = v;
  }
  float r2 = rv[l15 & 3];
  float s = __builtin_amdgcn_exp2f(__builtin_amdgcn_logf(r2) * 0.333333333333f);
#pragma unroll
  for (int itn = 0; itn < 8; itn++) {
    float one = 1.f + s;
    float fv = fmaf(s * one, one, -r2);
    float fp = one * fmaf(2.f, s, one);
    s = fmaxf(s - fv * __builtin_amdgcn_rcpf(fp), 0.f);
  }
  float myinv = -__builtin_amdgcn_rcpf(1.f + s);
#pragma unroll
  for (int r = 0; r < 4; r++) {
    float inv = __shfl(myinv, (lane & 48) | r);
    float* orow = out + (size_t)(rb + qd * 4 + r) * 96;
#pragma unroll
    for (int nt = 0; nt < 6; nt++)
      orow[nt * 16 + l15] = qa[nt][r] * inv;
  }
}

extern "C" void kernel_launch(void* const* d_in, const int* in_sizes, int n_in,
                              void* d_out, int out_size, void* d_ws, size_t ws_size,
                              hipStream_t stream) {
  const float* z  = (const float*)d_in[0];
  const float* t  = (const float*)d_in[1];
  const float* W1 = (const float*)d_in[2];
  const float* b1 = (const float*)d_in[3];
  const float* W2 = (const float*)d_in[4];
  const float* b2 = (const float*)d_in[5];
  const float* W3 = (const float*)d_in[6];
  const float* b3 = (const float*)d_in[7];
  float* out = (float*)d_out;
  int B = in_sizes[0] / 192;                 // 131072

  short* pw = (short*)d_ws;                  // 97,984 bytes used
  cvx_prep<<<190, 256, 0, stream>>>(W1, b1, W2, b2, W3, b3, pw);
  cvx_main<<<B / 256, 1024, 0, stream>>>(z, t, pw, out);
}